// Round 2
// baseline (605.117 us; speedup 1.0000x reference)
//
#include <hip/hip_runtime.h>

typedef __bf16 bf16_t;
typedef __bf16 bf16x8 __attribute__((ext_vector_type(8)));
typedef float  f32x4  __attribute__((ext_vector_type(4)));

#define T_STEPS 512
#define BATCH   2048
#define NS      64
#define FSTR    36

#define K_SIG  (-1.4426950408889634f)   // sigmoid: s = rcp(1+exp2(K_SIG*pre))
#define K_TANH ( 2.8853900817779268f)   // tanh:    t = 1-2*rcp(1+exp2(K_TANH*pre))

#define MFMA(A, B, C) __builtin_amdgcn_mfma_f32_16x16x32_bf16((A), (B), (C), 0, 0, 0)

// Single-wave LSTM tile: 16 batch rows x 32 hidden units, fully register-resident.
// Key trick: W_hh's contraction (column) order is permuted so that the MFMA
// C/D output layout of h (lane(q,m) holds units {4q+r, 16+4q+r}) IS the B-frag
// layout for the next step's h-GEMM (slot 8q+j <-> unit (j<4 ? 4q+j : 16+4q+j-4)).
// => no LDS, no barrier, no cross-lane ops in the 512-step recurrence.
__global__ __launch_bounds__(64, 1)
void lstm_policy_kernel(const float* __restrict__ x,
                        const float* __restrict__ W_ih,
                        const float* __restrict__ W_hh,
                        const float* __restrict__ b_ih,
                        const float* __restrict__ b_hh,
                        const float* __restrict__ W_d,
                        const float* __restrict__ b_d,
                        float* __restrict__ out)
{
  __shared__ float hf[16 * FSTR];        // final relu(h) for dense epilogue

  const int lane = threadIdx.x;          // 64 threads = 1 wave
  const int m    = lane & 15;            // batch row within tile / A-row
  const int q    = lane >> 4;            // 0..3
  const int row0 = blockIdx.x << 4;      // global batch row base

  // ---- preload W frags, pre-scaled by the activation input constants ----
  // a_ih[G][U][H]: A[row=unit_local=m][k=q*8+j (+32H)] of K*W_ih
  // a_hh[G][U]   : A[row=m][slot s=q*8+j] = K*W_hh[row][perm(s)]
  bf16x8 a_ih[4][2][2], a_hh[4][2];
  f32x4  bias[4][2];
  #pragma unroll
  for (int G = 0; G < 4; ++G) {
    const float k = (G == 2) ? K_TANH : K_SIG;
    #pragma unroll
    for (int U = 0; U < 2; ++U) {
      const int wrow = (G << 5) + (U << 4) + m;      // gate-major row of 4H=128
      const float* pih = W_ih + wrow * 64;
      const float* phh = W_hh + (wrow << 5);
      #pragma unroll
      for (int j = 0; j < 8; ++j) {
        a_ih[G][U][0][j] = (bf16_t)(k * pih[(q << 3) + j]);
        a_ih[G][U][1][j] = (bf16_t)(k * pih[32 + (q << 3) + j]);
        const int us = (j < 4) ? ((q << 2) + j) : (16 + (q << 2) + (j - 4));
        a_hh[G][U][j] = (bf16_t)(k * phh[us]);       // permuted contraction order
      }
      #pragma unroll
      for (int r = 0; r < 4; ++r) {
        const int u = (G << 5) + (U << 4) + (q << 2) + r;
        bias[G][U][r] = (b_ih[u] + b_hh[u]) * k;
      }
    }
  }

  const size_t xstep = (size_t)BATCH * NS;           // 1<<17 floats
  const float* xb = x + (size_t)row0 * NS;           // wave-uniform base
  const int    lo = m * NS + (q << 3);               // per-lane invariant offset

  // ---- x ring: slot s holds x[t], t%4==s (prologue: s1=x1,s2=x2,s3=x3,s0=x4) ----
  f32x4 xf[4][4];
  {
    const float* p1 = xb + 1 * xstep + lo;
    const float* p2 = xb + 2 * xstep + lo;
    const float* p3 = xb + 3 * xstep + lo;
    const float* p4 = xb + 4 * xstep + lo;
    xf[1][0]=*(const f32x4*)(p1); xf[1][1]=*(const f32x4*)(p1+4); xf[1][2]=*(const f32x4*)(p1+32); xf[1][3]=*(const f32x4*)(p1+36);
    xf[2][0]=*(const f32x4*)(p2); xf[2][1]=*(const f32x4*)(p2+4); xf[2][2]=*(const f32x4*)(p2+32); xf[2][3]=*(const f32x4*)(p2+36);
    xf[3][0]=*(const f32x4*)(p3); xf[3][1]=*(const f32x4*)(p3+4); xf[3][2]=*(const f32x4*)(p3+32); xf[3][3]=*(const f32x4*)(p3+36);
    xf[0][0]=*(const f32x4*)(p4); xf[0][1]=*(const f32x4*)(p4+4); xf[0][2]=*(const f32x4*)(p4+32); xf[0][3]=*(const f32x4*)(p4+36);
  }

  // ---- acc[2][G][U]: gate pre-activations (x-part + bias), pipelined one step ----
  f32x4 acc[2][4][2];
  {
    const float* p0 = xb + lo;
    f32x4 x0a = *(const f32x4*)(p0),      x0b = *(const f32x4*)(p0 + 4);
    f32x4 x0c = *(const f32x4*)(p0 + 32), x0d = *(const f32x4*)(p0 + 36);
    bf16x8 xA, xB;
    #pragma unroll
    for (int j = 0; j < 4; ++j) {
      xA[j] = (bf16_t)x0a[j]; xA[4+j] = (bf16_t)x0b[j];
      xB[j] = (bf16_t)x0c[j]; xB[4+j] = (bf16_t)x0d[j];
    }
    #pragma unroll
    for (int G = 0; G < 4; ++G)
      #pragma unroll
      for (int U = 0; U < 2; ++U) {
        acc[0][G][U] = MFMA(a_ih[G][U][0], xA, bias[G][U]);
        acc[0][G][U] = MFMA(a_ih[G][U][1], xB, acc[0][G][U]);
      }
  }

  float cst[2][4] = {{0,0,0,0},{0,0,0,0}};  // c-state in K_TANH-scaled basis
  bf16x8 hB = {};                            // h B-frag (h_{-1}=0), lane-local

  // STEP(P): one timestep. Chain: 8 h-MFMAs -> activations -> repack hB.
  // Off-chain: x-part MFMAs for t+1 + global prefetch fill the MFMA/VMEM pipes.
  #define STEP(P)                                                                     \
  do {                                                                                \
    const int tt = t + (P);                                                           \
    const int par = (P) & 1;                                                          \
    f32x4 gr[4][2];                                                                   \
    _Pragma("unroll")                                                                 \
    for (int G = 0; G < 4; ++G)                                                       \
      _Pragma("unroll")                                                               \
      for (int U = 0; U < 2; ++U)                                                     \
        gr[G][U] = MFMA(a_hh[G][U], hB, acc[par][G][U]);                              \
    /* x-part for t+1 into acc[par^1], then refill ring slot */                       \
    {                                                                                 \
      const int ns = ((P) + 1) & 3;                                                   \
      bf16x8 xA, xB;                                                                  \
      _Pragma("unroll")                                                               \
      for (int j = 0; j < 4; ++j) {                                                   \
        xA[j] = (bf16_t)xf[ns][0][j]; xA[4+j] = (bf16_t)xf[ns][1][j];                 \
        xB[j] = (bf16_t)xf[ns][2][j]; xB[4+j] = (bf16_t)xf[ns][3][j];                 \
      }                                                                               \
      _Pragma("unroll")                                                               \
      for (int G = 0; G < 4; ++G)                                                     \
        _Pragma("unroll")                                                             \
        for (int U = 0; U < 2; ++U) {                                                 \
          acc[par ^ 1][G][U] = MFMA(a_ih[G][U][0], xA, bias[G][U]);                   \
          acc[par ^ 1][G][U] = MFMA(a_ih[G][U][1], xB, acc[par ^ 1][G][U]);           \
        }                                                                             \
      int tp = tt + 5; if (tp > T_STEPS - 1) tp = T_STEPS - 1;                        \
      const float* pf = xb + (size_t)tp * xstep + lo;                                 \
      xf[ns][0] = *(const f32x4*)(pf);                                                \
      xf[ns][1] = *(const f32x4*)(pf + 4);                                            \
      xf[ns][2] = *(const f32x4*)(pf + 32);                                           \
      xf[ns][3] = *(const f32x4*)(pf + 36);                                           \
    }                                                                                 \
    /* activations: 8 lane-local cells; scales pre-folded into W/bias */              \
    _Pragma("unroll")                                                                 \
    for (int U = 0; U < 2; ++U)                                                       \
      _Pragma("unroll")                                                               \
      for (int r = 0; r < 4; ++r) {                                                   \
        const float iv = __builtin_amdgcn_rcpf(1.0f + __builtin_amdgcn_exp2f(gr[0][U][r])); \
        const float fv = __builtin_amdgcn_rcpf(1.0f + __builtin_amdgcn_exp2f(gr[1][U][r])); \
        const float rg = __builtin_amdgcn_rcpf(1.0f + __builtin_amdgcn_exp2f(gr[2][U][r])); \
        const float ov = __builtin_amdgcn_rcpf(1.0f + __builtin_amdgcn_exp2f(gr[3][U][r])); \
        const float gs = __builtin_fmaf(-2.0f * K_TANH, rg, K_TANH);  /* K*tanh(g) */ \
        const float cn = __builtin_fmaf(fv, cst[U][r], iv * gs);      /* K*c_new  */  \
        cst[U][r] = cn;                                                               \
        const float rh  = __builtin_amdgcn_rcpf(1.0f + __builtin_amdgcn_exp2f(cn));   \
        const float ov2 = ov + ov;                                                    \
        const float h   = __builtin_fmaf(-ov2, rh, ov);               /* o*tanh(c) */ \
        hB[(U << 2) + r] = (bf16_t)h;                                                 \
        if (tt == T_STEPS - 1) hf[m * FSTR + (U << 4) + (q << 2) + r] = fmaxf(h, 0.0f); \
      }                                                                               \
  } while (0)

  #pragma unroll 1
  for (int t = 0; t < T_STEPS; t += 4) {
    STEP(0);
    STEP(1);
    STEP(2);
    STEP(3);
  }
  #undef STEP

  __syncthreads();   // single wave: compiles to a waitcnt; orders hf writes/reads

  // dense epilogue: out[row][a] = relu(h_T[row]) . W_d[a] + b_d[a]
  if (lane < 48) {
    const int r = lane / 3;
    const int a = lane - r * 3;
    float s = b_d[a];
    #pragma unroll
    for (int u = 0; u < 32; ++u)
      s += hf[r * FSTR + u] * W_d[a * 32 + u];
    out[(size_t)(row0 + r) * 3 + a] = s;
  }
}

extern "C" void kernel_launch(void* const* d_in, const int* in_sizes, int n_in,
                              void* d_out, int out_size, void* d_ws, size_t ws_size,
                              hipStream_t stream) {
  const float* x    = (const float*)d_in[0];
  const float* W_ih = (const float*)d_in[1];
  const float* W_hh = (const float*)d_in[2];
  const float* b_ih = (const float*)d_in[3];
  const float* b_hh = (const float*)d_in[4];
  const float* W_d  = (const float*)d_in[5];
  const float* b_d  = (const float*)d_in[6];
  float* out = (float*)d_out;

  dim3 grid(BATCH / 16);   // 128 independent single-wave chains
  dim3 block(64);          // 1 wave: no barriers anywhere in the recurrence
  hipLaunchKernelGGL(lstm_policy_kernel, grid, block, 0, stream,
                     x, W_ih, W_hh, b_ih, b_hh, W_d, b_d, out);
}

// Round 3
// 604.080 us; speedup vs baseline: 1.0017x; 1.0017x over previous
//
#include <hip/hip_runtime.h>

typedef __bf16 bf16_t;
typedef __bf16 bf16x8 __attribute__((ext_vector_type(8)));
typedef float  f32x4  __attribute__((ext_vector_type(4)));

#define T_STEPS 512
#define BATCH   2048
#define NS      64
#define FSTR    36

#define K_SIG  (-1.4426950408889634f)   // sigmoid: s = rcp(1+exp2(K_SIG*pre))
#define K_TANH ( 2.8853900817779268f)   // tanh:    t = 1-2*rcp(1+exp2(K_TANH*pre))

#define MFMA(A, B, C) __builtin_amdgcn_mfma_f32_16x16x32_bf16((A), (B), (C), 0, 0, 0)

// Single-wave LSTM tile: 16 batch rows x 32 hidden units, fully register-resident.
// W_hh's contraction order is permuted so the MFMA C/D layout of h IS the B-frag
// layout for the next step's h-GEMM => no LDS/barrier/cross-lane in the recurrence.
// amdgpu_waves_per_eu(1,1): occupancy is 1 wave/EU by construction (128 blocks on
// 256 CUs); cap it so the allocator uses the full 512-reg unified file, no spills.
__global__ __launch_bounds__(64, 1) __attribute__((amdgpu_waves_per_eu(1, 1)))
void lstm_policy_kernel(const float* __restrict__ x,
                        const float* __restrict__ W_ih,
                        const float* __restrict__ W_hh,
                        const float* __restrict__ b_ih,
                        const float* __restrict__ b_hh,
                        const float* __restrict__ W_d,
                        const float* __restrict__ b_d,
                        float* __restrict__ out)
{
  __shared__ float hf[16 * FSTR];        // final relu(h) for dense epilogue

  const int lane = threadIdx.x;          // 64 threads = 1 wave
  const int m    = lane & 15;            // batch row within tile / B-col
  const int q    = lane >> 4;            // 0..3
  const int row0 = blockIdx.x << 4;      // global batch row base

  // ---- preload W frags, pre-scaled by the activation input constants ----
  bf16x8 a_ih[4][2][2], a_hh[4][2];
  f32x4  bias[4][2];
  #pragma unroll
  for (int G = 0; G < 4; ++G) {
    const float k = (G == 2) ? K_TANH : K_SIG;
    #pragma unroll
    for (int U = 0; U < 2; ++U) {
      const int wrow = (G << 5) + (U << 4) + m;      // gate-major row of 4H=128
      const float* pih = W_ih + wrow * 64;
      const float* phh = W_hh + (wrow << 5);
      #pragma unroll
      for (int j = 0; j < 8; ++j) {
        a_ih[G][U][0][j] = (bf16_t)(k * pih[(q << 3) + j]);
        a_ih[G][U][1][j] = (bf16_t)(k * pih[32 + (q << 3) + j]);
        const int us = (j < 4) ? ((q << 2) + j) : (16 + (q << 2) + (j - 4));
        a_hh[G][U][j] = (bf16_t)(k * phh[us]);       // permuted contraction order
      }
      #pragma unroll
      for (int r = 0; r < 4; ++r) {
        const int u = (G << 5) + (U << 4) + (q << 2) + r;
        bias[G][U][r] = (b_ih[u] + b_hh[u]) * k;
      }
    }
  }

  const size_t xstep = (size_t)BATCH * NS;           // 1<<17 floats
  const float* xb = x + (size_t)row0 * NS;           // wave-uniform base
  const int    lo = m * NS + (q << 3);               // per-lane invariant offset

  // ---- x ring: slot s holds x[t], t%4==s (prologue: s1=x1,s2=x2,s3=x3,s0=x4) ----
  f32x4 xf[4][4];
  {
    const float* p1 = xb + 1 * xstep + lo;
    const float* p2 = xb + 2 * xstep + lo;
    const float* p3 = xb + 3 * xstep + lo;
    const float* p4 = xb + 4 * xstep + lo;
    xf[1][0]=*(const f32x4*)(p1); xf[1][1]=*(const f32x4*)(p1+4); xf[1][2]=*(const f32x4*)(p1+32); xf[1][3]=*(const f32x4*)(p1+36);
    xf[2][0]=*(const f32x4*)(p2); xf[2][1]=*(const f32x4*)(p2+4); xf[2][2]=*(const f32x4*)(p2+32); xf[2][3]=*(const f32x4*)(p2+36);
    xf[3][0]=*(const f32x4*)(p3); xf[3][1]=*(const f32x4*)(p3+4); xf[3][2]=*(const f32x4*)(p3+32); xf[3][3]=*(const f32x4*)(p3+36);
    xf[0][0]=*(const f32x4*)(p4); xf[0][1]=*(const f32x4*)(p4+4); xf[0][2]=*(const f32x4*)(p4+32); xf[0][3]=*(const f32x4*)(p4+36);
  }

  // ---- acc[G][U]: gate pre-activations (x-part + bias), single-buffered.
  // Consumed as C-in by the h-MFMAs at step start, then immediately rebuilt
  // for t+1 (pure WAR) — halves acc register footprint vs double-buffer.
  f32x4 acc[4][2];
  {
    const float* p0 = xb + lo;
    f32x4 x0a = *(const f32x4*)(p0),      x0b = *(const f32x4*)(p0 + 4);
    f32x4 x0c = *(const f32x4*)(p0 + 32), x0d = *(const f32x4*)(p0 + 36);
    bf16x8 xA, xB;
    #pragma unroll
    for (int j = 0; j < 4; ++j) {
      xA[j] = (bf16_t)x0a[j]; xA[4+j] = (bf16_t)x0b[j];
      xB[j] = (bf16_t)x0c[j]; xB[4+j] = (bf16_t)x0d[j];
    }
    #pragma unroll
    for (int G = 0; G < 4; ++G)
      #pragma unroll
      for (int U = 0; U < 2; ++U) {
        acc[G][U] = MFMA(a_ih[G][U][0], xA, bias[G][U]);
        acc[G][U] = MFMA(a_ih[G][U][1], xB, acc[G][U]);
      }
  }

  float cst[2][4] = {{0,0,0,0},{0,0,0,0}};  // c-state in K_TANH-scaled basis
  bf16x8 hB = {};                            // h B-frag (h_{-1}=0), lane-local

  // STEP(P): one timestep. Chain: 8 h-MFMAs -> activations -> repack hB.
  // Off-chain: x-part MFMAs for t+1 + global prefetch fill the MFMA/VMEM pipes.
  #define STEP(P)                                                                     \
  do {                                                                                \
    const int tt = t + (P);                                                           \
    f32x4 gr[4][2];                                                                   \
    _Pragma("unroll")                                                                 \
    for (int G = 0; G < 4; ++G)                                                       \
      _Pragma("unroll")                                                               \
      for (int U = 0; U < 2; ++U)                                                     \
        gr[G][U] = MFMA(a_hh[G][U], hB, acc[G][U]);                                   \
    /* x-part for t+1 overwrites acc (WAR), then refill ring slot */                  \
    {                                                                                 \
      const int ns = ((P) + 1) & 3;                                                   \
      bf16x8 xA, xB;                                                                  \
      _Pragma("unroll")                                                               \
      for (int j = 0; j < 4; ++j) {                                                   \
        xA[j] = (bf16_t)xf[ns][0][j]; xA[4+j] = (bf16_t)xf[ns][1][j];                 \
        xB[j] = (bf16_t)xf[ns][2][j]; xB[4+j] = (bf16_t)xf[ns][3][j];                 \
      }                                                                               \
      _Pragma("unroll")                                                               \
      for (int G = 0; G < 4; ++G)                                                     \
        _Pragma("unroll")                                                             \
        for (int U = 0; U < 2; ++U) {                                                 \
          acc[G][U] = MFMA(a_ih[G][U][0], xA, bias[G][U]);                            \
          acc[G][U] = MFMA(a_ih[G][U][1], xB, acc[G][U]);                             \
        }                                                                             \
      int tp = tt + 5; if (tp > T_STEPS - 1) tp = T_STEPS - 1;                        \
      const float* pf = xb + (size_t)tp * xstep + lo;                                 \
      xf[ns][0] = *(const f32x4*)(pf);                                                \
      xf[ns][1] = *(const f32x4*)(pf + 4);                                            \
      xf[ns][2] = *(const f32x4*)(pf + 32);                                           \
      xf[ns][3] = *(const f32x4*)(pf + 36);                                           \
    }                                                                                 \
    /* activations: 8 lane-local cells; scales pre-folded into W/bias */              \
    _Pragma("unroll")                                                                 \
    for (int U = 0; U < 2; ++U)                                                       \
      _Pragma("unroll")                                                               \
      for (int r = 0; r < 4; ++r) {                                                   \
        const float iv = __builtin_amdgcn_rcpf(1.0f + __builtin_amdgcn_exp2f(gr[0][U][r])); \
        const float fv = __builtin_amdgcn_rcpf(1.0f + __builtin_amdgcn_exp2f(gr[1][U][r])); \
        const float rg = __builtin_amdgcn_rcpf(1.0f + __builtin_amdgcn_exp2f(gr[2][U][r])); \
        const float ov = __builtin_amdgcn_rcpf(1.0f + __builtin_amdgcn_exp2f(gr[3][U][r])); \
        const float gs = __builtin_fmaf(-2.0f * K_TANH, rg, K_TANH);  /* K*tanh(g) */ \
        const float cn = __builtin_fmaf(fv, cst[U][r], iv * gs);      /* K*c_new  */  \
        cst[U][r] = cn;                                                               \
        const float rh  = __builtin_amdgcn_rcpf(1.0f + __builtin_amdgcn_exp2f(cn));   \
        const float ov2 = ov + ov;                                                    \
        const float h   = __builtin_fmaf(-ov2, rh, ov);               /* o*tanh(c) */ \
        hB[(U << 2) + r] = (bf16_t)h;                                                 \
        if (tt == T_STEPS - 1) hf[m * FSTR + (U << 4) + (q << 2) + r] = fmaxf(h, 0.0f); \
      }                                                                               \
  } while (0)

  #pragma unroll 1
  for (int t = 0; t < T_STEPS; t += 4) {
    STEP(0);
    STEP(1);
    STEP(2);
    STEP(3);
  }
  #undef STEP

  __syncthreads();   // single wave: orders hf writes/reads

  // dense epilogue: out[row][a] = relu(h_T[row]) . W_d[a] + b_d[a]
  if (lane < 48) {
    const int r = lane / 3;
    const int a = lane - r * 3;
    float s = b_d[a];
    #pragma unroll
    for (int u = 0; u < 32; ++u)
      s += hf[r * FSTR + u] * W_d[a * 32 + u];
    out[(size_t)(row0 + r) * 3 + a] = s;
  }
}

extern "C" void kernel_launch(void* const* d_in, const int* in_sizes, int n_in,
                              void* d_out, int out_size, void* d_ws, size_t ws_size,
                              hipStream_t stream) {
  const float* x    = (const float*)d_in[0];
  const float* W_ih = (const float*)d_in[1];
  const float* W_hh = (const float*)d_in[2];
  const float* b_ih = (const float*)d_in[3];
  const float* b_hh = (const float*)d_in[4];
  const float* W_d  = (const float*)d_in[5];
  const float* b_d  = (const float*)d_in[6];
  float* out = (float*)d_out;

  dim3 grid(BATCH / 16);   // 128 independent single-wave chains
  dim3 block(64);          // 1 wave: no barriers anywhere in the recurrence
  hipLaunchKernelGGL(lstm_policy_kernel, grid, block, 0, stream,
                     x, W_ih, W_hh, b_ih, b_hh, W_d, b_d, out);
}

// Round 4
// 526.627 us; speedup vs baseline: 1.1490x; 1.1471x over previous
//
#include <hip/hip_runtime.h>

typedef __bf16 bf16_t;
typedef __bf16 bf16x8 __attribute__((ext_vector_type(8)));
typedef float  f32x4  __attribute__((ext_vector_type(4)));
typedef unsigned int u32x4 __attribute__((ext_vector_type(4)));

#define T_STEPS 512
#define BATCH   2048
#define NS      64
#define FSTR    36

#define K_SIG  (-1.4426950408889634f)   // sigmoid: s = rcp(1+exp2(K_SIG*pre))
#define K_TANH ( 2.8853900817779268f)   // tanh:    t = 1-2*rcp(1+exp2(K_TANH*pre))

#define MFMA(A, B, C) __builtin_amdgcn_mfma_f32_16x16x32_bf16((A), (B), (C), 0, 0, 0)
#define RCPE(xv) __builtin_amdgcn_rcpf(1.0f + __builtin_amdgcn_exp2f(xv))

// lgkm-only barrier: global x-prefetch loads stay in flight across it
__device__ __forceinline__ void barrier_lgkm() {
  asm volatile("s_waitcnt lgkmcnt(0)\n\ts_barrier" ::: "memory");
}

// 4-wave cooperative LSTM chain: 16 batch rows x 32 hidden units per block.
// The serial recurrence is trans-pipe-bound (10 v_exp/v_rcp per cell); spread
// the 8 cells/lane over 4 waves (4 SIMDs = 4 trans pipes): each wave computes
// MFMAs for its unit-tile U=w>>1 (redundant with its pair wave - MFMA pipe is
// idle) but activations for only 2 cells/lane. h is re-broadcast via one
// packed-u32 LDS write + 4 reads per step (double-buffered, one barrier).
// W_hh contraction order is permuted so the MFMA C/D layout of h IS the
// B-frag layout for the next step's h-GEMM (slot 8q+j <-> unit j<4?4q+j:16+4q+j-4).
__global__ __launch_bounds__(256, 1) __attribute__((amdgpu_waves_per_eu(1, 1)))
void lstm_policy_kernel(const float* __restrict__ x,
                        const float* __restrict__ W_ih,
                        const float* __restrict__ W_hh,
                        const float* __restrict__ b_ih,
                        const float* __restrict__ b_hh,
                        const float* __restrict__ W_d,
                        const float* __restrict__ b_d,
                        float* __restrict__ out)
{
  __shared__ unsigned int hlds[2][4][64];  // [parity][wave][lane] packed 2xbf16
  __shared__ float hf[16 * FSTR];          // final relu(h) for dense epilogue

  const int tid  = threadIdx.x;
  const int wv   = tid >> 6;               // 0..3
  const int lane = tid & 63;
  const int m    = lane & 15;              // batch row within tile (B-col)
  const int q    = lane >> 4;              // 0..3
  const int U    = wv >> 1;                // this wave's unit-tile (0 or 1)
  const int rsel = wv & 1;                 // 0: cells r=0,1   1: cells r=2,3
  const int row0 = blockIdx.x << 4;        // global batch row base

  // ---- preload W frags for our U, pre-scaled by activation input constants ----
  bf16x8 a_ih[4][2], a_hh[4];
  f32x4  bias[4];
  #pragma unroll
  for (int G = 0; G < 4; ++G) {
    const float k = (G == 2) ? K_TANH : K_SIG;
    const int wrow = (G << 5) + (U << 4) + m;      // gate-major row of 4H=128
    const float* pih = W_ih + wrow * 64;
    const float* phh = W_hh + (wrow << 5);
    #pragma unroll
    for (int j = 0; j < 8; ++j) {
      a_ih[G][0][j] = (bf16_t)(k * pih[(q << 3) + j]);
      a_ih[G][1][j] = (bf16_t)(k * pih[32 + (q << 3) + j]);
      const int us = (j < 4) ? ((q << 2) + j) : (16 + (q << 2) + (j - 4));
      a_hh[G][j] = (bf16_t)(k * phh[us]);          // permuted contraction order
    }
    #pragma unroll
    for (int r = 0; r < 4; ++r) {
      const int u = (G << 5) + (U << 4) + (q << 2) + r;
      bias[G][r] = (b_ih[u] + b_hh[u]) * k;
    }
  }

  const size_t xstep = (size_t)BATCH * NS;           // 1<<17 floats
  const float* xb = x + (size_t)row0 * NS;           // wave-uniform base
  const int    lo = m * NS + (q << 3);               // per-lane invariant offset

  // ---- x ring: slot s holds x[t], t%4==s (prologue: s1=x1,s2=x2,s3=x3,s0=x4) ----
  f32x4 xf[4][4];
  {
    const float* p1 = xb + 1 * xstep + lo;
    const float* p2 = xb + 2 * xstep + lo;
    const float* p3 = xb + 3 * xstep + lo;
    const float* p4 = xb + 4 * xstep + lo;
    xf[1][0]=*(const f32x4*)(p1); xf[1][1]=*(const f32x4*)(p1+4); xf[1][2]=*(const f32x4*)(p1+32); xf[1][3]=*(const f32x4*)(p1+36);
    xf[2][0]=*(const f32x4*)(p2); xf[2][1]=*(const f32x4*)(p2+4); xf[2][2]=*(const f32x4*)(p2+32); xf[2][3]=*(const f32x4*)(p2+36);
    xf[3][0]=*(const f32x4*)(p3); xf[3][1]=*(const f32x4*)(p3+4); xf[3][2]=*(const f32x4*)(p3+32); xf[3][3]=*(const f32x4*)(p3+36);
    xf[0][0]=*(const f32x4*)(p4); xf[0][1]=*(const f32x4*)(p4+4); xf[0][2]=*(const f32x4*)(p4+32); xf[0][3]=*(const f32x4*)(p4+36);
  }

  // ---- acc[G]: gate pre-activations for our U (x-part + bias), single-buffered ----
  f32x4 acc[4];
  {
    const float* p0 = xb + lo;
    f32x4 x0a = *(const f32x4*)(p0),      x0b = *(const f32x4*)(p0 + 4);
    f32x4 x0c = *(const f32x4*)(p0 + 32), x0d = *(const f32x4*)(p0 + 36);
    bf16x8 xA, xB;
    #pragma unroll
    for (int j = 0; j < 4; ++j) {
      xA[j] = (bf16_t)x0a[j]; xA[4+j] = (bf16_t)x0b[j];
      xB[j] = (bf16_t)x0c[j]; xB[4+j] = (bf16_t)x0d[j];
    }
    #pragma unroll
    for (int G = 0; G < 4; ++G) {
      acc[G] = MFMA(a_ih[G][0], xA, bias[G]);
      acc[G] = MFMA(a_ih[G][1], xB, acc[G]);
    }
  }

  float cst[2] = {0.0f, 0.0f};   // c-state for our 2 cells (K_TANH-scaled basis)
  bf16x8 hB = {};                // full h B-frag (h_{-1}=0), rebuilt each step

  // one cell's activation math (literal RR index -> no dynamic vector indexing)
  #define CELL(RR, E, HOUT)                                                         \
    {                                                                               \
      const float iv = RCPE(gr[0][RR]);                                             \
      const float fv = RCPE(gr[1][RR]);                                             \
      const float rg = RCPE(gr[2][RR]);                                             \
      const float ov = RCPE(gr[3][RR]);                                             \
      const float gs = __builtin_fmaf(-2.0f * K_TANH, rg, K_TANH);  /* K*tanh(g) */ \
      const float cn = __builtin_fmaf(fv, cst[E], iv * gs);         /* K*c_new  */  \
      cst[E] = cn;                                                                  \
      const float rh  = RCPE(cn);                                                   \
      const float ov2 = ov + ov;                                                    \
      HOUT = __builtin_fmaf(-ov2, rh, ov);                          /* o*tanh(c) */ \
      if (tt == T_STEPS - 1) hf[m * FSTR + (U << 4) + (q << 2) + RR] = fmaxf(HOUT, 0.0f); \
    }

  // STEP(P): one timestep. gr-MFMA -> 2-cell activations -> pack/write -> barrier
  // -> issue 4 h-reads; x-part for t+1 fills the ds_read latency -> assemble hB.
  #define STEP(P)                                                                   \
  do {                                                                              \
    const int tt  = t + (P);                                                        \
    const int par = (P) & 1;                                                        \
    f32x4 gr[4];                                                                    \
    _Pragma("unroll")                                                               \
    for (int G = 0; G < 4; ++G)                                                     \
      gr[G] = MFMA(a_hh[G], hB, acc[G]);                                            \
    float h0, h1;                                                                   \
    if (rsel == 0) { CELL(0, 0, h0) CELL(1, 1, h1) }                                \
    else           { CELL(2, 0, h0) CELL(3, 1, h1) }                                \
    {                                                                               \
      const unsigned int s0 = __builtin_bit_cast(unsigned short, (bf16_t)h0);       \
      const unsigned int s1 = __builtin_bit_cast(unsigned short, (bf16_t)h1);       \
      hlds[par][wv][lane] = s0 | (s1 << 16);                                        \
    }                                                                               \
    barrier_lgkm();                                                                 \
    const unsigned int w0 = hlds[par][0][lane];                                     \
    const unsigned int w1 = hlds[par][1][lane];                                     \
    const unsigned int w2 = hlds[par][2][lane];                                     \
    const unsigned int w3 = hlds[par][3][lane];                                     \
    /* x-part for t+1 overwrites acc (WAR); fills the ds_read latency */            \
    {                                                                               \
      const int ns = ((P) + 1) & 3;                                                 \
      bf16x8 xA, xB;                                                                \
      _Pragma("unroll")                                                             \
      for (int j = 0; j < 4; ++j) {                                                 \
        xA[j] = (bf16_t)xf[ns][0][j]; xA[4+j] = (bf16_t)xf[ns][1][j];               \
        xB[j] = (bf16_t)xf[ns][2][j]; xB[4+j] = (bf16_t)xf[ns][3][j];               \
      }                                                                             \
      _Pragma("unroll")                                                             \
      for (int G = 0; G < 4; ++G) {                                                 \
        acc[G] = MFMA(a_ih[G][0], xA, bias[G]);                                     \
        acc[G] = MFMA(a_ih[G][1], xB, acc[G]);                                      \
      }                                                                             \
      int tp = tt + 5; if (tp > T_STEPS - 1) tp = T_STEPS - 1;                      \
      const float* pf = xb + (size_t)tp * xstep + lo;                               \
      xf[ns][0] = *(const f32x4*)(pf);                                              \
      xf[ns][1] = *(const f32x4*)(pf + 4);                                          \
      xf[ns][2] = *(const f32x4*)(pf + 32);                                         \
      xf[ns][3] = *(const f32x4*)(pf + 36);                                         \
    }                                                                               \
    {                                                                               \
      u32x4 hw; hw[0] = w0; hw[1] = w1; hw[2] = w2; hw[3] = w3;                     \
      hB = __builtin_bit_cast(bf16x8, hw);                                          \
    }                                                                               \
  } while (0)

  #pragma unroll 1
  for (int t = 0; t < T_STEPS; t += 4) {
    STEP(0);
    STEP(1);
    STEP(2);
    STEP(3);
  }
  #undef STEP
  #undef CELL

  __syncthreads();

  // dense epilogue: out[row][a] = relu(h_T[row]) . W_d[a] + b_d[a]
  if (tid < 48) {
    const int r = tid / 3;
    const int a = tid - r * 3;
    float s = b_d[a];
    #pragma unroll
    for (int u = 0; u < 32; ++u)
      s += hf[r * FSTR + u] * W_d[a * 32 + u];
    out[(size_t)(row0 + r) * 3 + a] = s;
  }
}

extern "C" void kernel_launch(void* const* d_in, const int* in_sizes, int n_in,
                              void* d_out, int out_size, void* d_ws, size_t ws_size,
                              hipStream_t stream) {
  const float* x    = (const float*)d_in[0];
  const float* W_ih = (const float*)d_in[1];
  const float* W_hh = (const float*)d_in[2];
  const float* b_ih = (const float*)d_in[3];
  const float* b_hh = (const float*)d_in[4];
  const float* W_d  = (const float*)d_in[5];
  const float* b_d  = (const float*)d_in[6];
  float* out = (float*)d_out;

  dim3 grid(BATCH / 16);   // 128 chains, one per block
  dim3 block(256);         // 4 waves: activation work split across 4 trans pipes
  hipLaunchKernelGGL(lstm_policy_kernel, grid, block, 0, stream,
                     x, W_ih, W_hh, b_ih, b_hh, W_d, b_d, out);
}